// Round 1
// baseline (629.806 us; speedup 1.0000x reference)
//
#include <hip/hip_runtime.h>
#include <hip/hip_bf16.h>

// Problem constants (from reference)
#define ITEM_NUM 100000
#define PROTO_NUM 1024
#define USER_NUM 100000
#define DOMAIN_NUM 4
#define DIM 128
#define BATCH 4096
#define HIST 50
#define EPS 1e-5f

// GEMM tiling
#define BM 64
#define BN 64
#define BN2 32
#define BK 32

// Workspace layout (floats). Total ws use = 384 + 4096*256 floats ≈ 4.2 MB.
// z1/z2 live in d_out regions (out_pu/out_pd) as scratch; k_gather rewrites
// them with the final prompt gathers at the end of the pipeline.
#define STATS_OFF 0            // s1[128], sq1[128], s2[64], sq2[64] = 384
#define INTER_OFF 384          // [4096, 256] (16B-aligned: 384*4 = 1536)

__device__ __forceinline__ int clampi(int v, int hi) {
    // JAX gather semantics: indices are clipped to [0, hi]
    return v < 0 ? 0 : (v > hi ? hi : v);
}

// ------------------------------------------------------------- per-sample
// One block per sample b, 128 threads (one per feature dim d).
// h_u: 1024-bit presence mask -> index list -> 4-way unrolled row accumulate.
__global__ __launch_bounds__(128) void k_sample(
    const int* __restrict__ nodes_d, const int* __restrict__ inter_items,
    const int* __restrict__ top_n_index, const float* __restrict__ prototypes,
    const float* __restrict__ domain_prompt,
    float* __restrict__ out_hu, float* __restrict__ inter_feat) {
    const int b = blockIdx.x;
    const int d = threadIdx.x;
    __shared__ unsigned int bmask[32];
    __shared__ unsigned short idxlist[400];
    if (d < 32) bmask[d] = 0u;
    __syncthreads();
    // 100 gather slots: d<50 -> text view, 50<=d<100 -> visual view
    if (d < 2 * HIST) {
        int item = inter_items[b * HIST + (d % HIST)];
        int row = clampi(item + (d >= HIST ? ITEM_NUM : 0), 2 * ITEM_NUM - 1);
        int4 q = *(const int4*)(top_n_index + (size_t)row * 4);
        // JAX scatter drops OOB updates -> skip, don't clamp
        if ((unsigned)q.x < PROTO_NUM) atomicOr(&bmask[((unsigned)q.x) >> 5], 1u << (q.x & 31));
        if ((unsigned)q.y < PROTO_NUM) atomicOr(&bmask[((unsigned)q.y) >> 5], 1u << (q.y & 31));
        if ((unsigned)q.z < PROTO_NUM) atomicOr(&bmask[((unsigned)q.z) >> 5], 1u << (q.z & 31));
        if ((unsigned)q.w < PROTO_NUM) atomicOr(&bmask[((unsigned)q.w) >> 5], 1u << (q.w & 31));
    }
    __syncthreads();
    int cnt = 0;
#pragma unroll
    for (int w = 0; w < 32; ++w) cnt += __popc(bmask[w]);
    // Extract set bits into a compact index list (threads 0..31, one word each).
    if (d < 32) {
        int base = 0;
        for (int w = 0; w < d; ++w) base += __popc(bmask[w]);
        unsigned int word = bmask[d];
        while (word) {
            int bit = __ffs(word) - 1;
            word &= word - 1;
            idxlist[base++] = (unsigned short)((d << 5) + bit);
        }
    }
    __syncthreads();
    // 4 independent load streams -> 4x memory-level parallelism (L2-resident rows).
    float a0 = 0.f, a1 = 0.f, a2 = 0.f, a3 = 0.f;
    int i = 0;
    for (; i + 4 <= cnt; i += 4) {
        int r0 = idxlist[i + 0], r1 = idxlist[i + 1];
        int r2 = idxlist[i + 2], r3 = idxlist[i + 3];
        a0 += prototypes[(size_t)r0 * DIM + d];
        a1 += prototypes[(size_t)r1 * DIM + d];
        a2 += prototypes[(size_t)r2 * DIM + d];
        a3 += prototypes[(size_t)r3 * DIM + d];
    }
    for (; i < cnt; ++i) a0 += prototypes[(size_t)idxlist[i] * DIM + d];
    float hu = ((a0 + a1) + (a2 + a3)) / (float)cnt;
    int dom = clampi(nodes_d[b], DOMAIN_NUM - 1);
    float pd = domain_prompt[(size_t)dom * DIM + d];
    out_hu[(size_t)b * DIM + d] = hu;
    inter_feat[(size_t)b * 256 + d] = hu + pd;  // h_u_hat
}

#define FMA16(a, bb)                                                                              \
    acc[0][0] += a.x * bb.x; acc[0][1] += a.x * bb.y; acc[0][2] += a.x * bb.z; acc[0][3] += a.x * bb.w; \
    acc[1][0] += a.y * bb.x; acc[1][1] += a.y * bb.y; acc[1][2] += a.y * bb.z; acc[1][3] += a.y * bb.w; \
    acc[2][0] += a.z * bb.x; acc[2][1] += a.z * bb.y; acc[2][2] += a.z * bb.z; acc[2][3] += a.z * bb.w; \
    acc[3][0] += a.w * bb.x; acc[3][1] += a.w * bb.y; acc[3][2] += a.w * bb.z; acc[3][3] += a.w * bb.w;

// ----------------------------------------------- gathered-row e-feature GEMM
// inter_feat[:,128:256] = (xcat(nodes_v) - bcat) @ Wcat.T + item_prompt[nodes_v]
// xcat = [pre_text row (384) | pre_visual row (768)], K = 1152.
// 64x32 tiles -> 256 blocks (one per CU). Block (0,0) also zeroes BN stats.
__global__ __launch_bounds__(256) void k_gemm_e(
    const int* __restrict__ nodes_v,
    const float* __restrict__ pre_text, const float* __restrict__ pre_visual,
    const float* __restrict__ Wt, const float* __restrict__ bt,
    const float* __restrict__ Wv, const float* __restrict__ bv,
    const float* __restrict__ item_prompt, float* __restrict__ inter_feat,
    float* __restrict__ stats) {
    __shared__ float As[BK][BM];
    __shared__ float Bs[BK][BN2];
    const int tid = threadIdx.x;
    const int m0 = blockIdx.x * BM;
    const int n0 = blockIdx.y * BN2;
    if (blockIdx.x == 0 && blockIdx.y == 0) {  // stats consumed only by k_gemm1 (next launch)
        stats[tid] = 0.f;
        if (tid < 128) stats[256 + tid] = 0.f;
    }
    const int tm = tid >> 4, tn = tid & 15;
    const int am = tid >> 2, aq = tid & 3;  // A staging: row am (0..63), k-chunk aq*8
    const int arow = clampi(nodes_v[m0 + am], ITEM_NUM - 1);
    const float* __restrict__ at = pre_text + (size_t)arow * 384;
    const float* __restrict__ av = pre_visual + (size_t)arow * 768;
    const float* __restrict__ wt = Wt + (size_t)(n0 + am) * 384;  // only tid<128 used (rows 0..31)
    const float* __restrict__ wv = Wv + (size_t)(n0 + am) * 768;
    float acc[4][2] = {};
    for (int k0 = 0; k0 < 1152; k0 += BK) {
        const int kb = aq * 8;
        const int kg = k0 + kb;
        float4 x0, x1, c0, c1;
        if (kg < 384) {  // uniform per block (384 % 32 == 0)
            x0 = *(const float4*)(at + kg);  x1 = *(const float4*)(at + kg + 4);
            c0 = *(const float4*)(bt + kg);  c1 = *(const float4*)(bt + kg + 4);
        } else {
            int kh = kg - 384;
            x0 = *(const float4*)(av + kh);  x1 = *(const float4*)(av + kh + 4);
            c0 = *(const float4*)(bv + kh);  c1 = *(const float4*)(bv + kh + 4);
        }
        As[kb + 0][am] = x0.x - c0.x; As[kb + 1][am] = x0.y - c0.y;
        As[kb + 2][am] = x0.z - c0.z; As[kb + 3][am] = x0.w - c0.w;
        As[kb + 4][am] = x1.x - c1.x; As[kb + 5][am] = x1.y - c1.y;
        As[kb + 6][am] = x1.z - c1.z; As[kb + 7][am] = x1.w - c1.w;
        if (tid < 128) {  // B staging: 32 rows x 32 k
            float4 w0, w1;
            if (kg < 384) {
                w0 = *(const float4*)(wt + kg);  w1 = *(const float4*)(wt + kg + 4);
            } else {
                int kh = kg - 384;
                w0 = *(const float4*)(wv + kh);  w1 = *(const float4*)(wv + kh + 4);
            }
            Bs[kb + 0][am] = w0.x; Bs[kb + 1][am] = w0.y; Bs[kb + 2][am] = w0.z; Bs[kb + 3][am] = w0.w;
            Bs[kb + 4][am] = w1.x; Bs[kb + 5][am] = w1.y; Bs[kb + 6][am] = w1.z; Bs[kb + 7][am] = w1.w;
        }
        __syncthreads();
#pragma unroll
        for (int kk = 0; kk < BK; ++kk) {
            float4 a = *(const float4*)&As[kk][tm * 4];
            float2 bb = *(const float2*)&Bs[kk][tn * 2];
            acc[0][0] += a.x * bb.x; acc[0][1] += a.x * bb.y;
            acc[1][0] += a.y * bb.x; acc[1][1] += a.y * bb.y;
            acc[2][0] += a.z * bb.x; acc[2][1] += a.z * bb.y;
            acc[3][0] += a.w * bb.x; acc[3][1] += a.w * bb.y;
        }
        __syncthreads();
    }
#pragma unroll
    for (int i = 0; i < 4; ++i) {
        int m = m0 + tm * 4 + i;
        int v = clampi(nodes_v[m], ITEM_NUM - 1);
        const float* __restrict__ ip = item_prompt + (size_t)v * DIM + n0 + tn * 2;
        float2 r;
        r.x = acc[i][0] + ip[0];
        r.y = acc[i][1] + ip[1];
        *(float2*)(inter_feat + (size_t)m * 256 + 128 + n0 + tn * 2) = r;
    }
}

// --------------------------------------------------- layer 1: z1 = relu(inter@W1.T + b1)
__global__ __launch_bounds__(256) void k_gemm1(
    const float* __restrict__ inter_feat, const float* __restrict__ W1,
    const float* __restrict__ b1, float* __restrict__ z1, float* __restrict__ stats) {
    __shared__ float As[BK][BM];
    __shared__ float Bs[BK][BN];
    __shared__ float csum[BN], csq[BN];
    const int tid = threadIdx.x;
    const int m0 = blockIdx.x * BM;
    const int n0 = blockIdx.y * BN;
    const int tm = tid >> 4, tn = tid & 15;
    const int am = tid >> 2, aq = tid & 3;
    const float* __restrict__ arow = inter_feat + (size_t)(m0 + am) * 256;
    const float* __restrict__ brow = W1 + (size_t)(n0 + am) * 256;
    float acc[4][4] = {};
    for (int k0 = 0; k0 < 256; k0 += BK) {
        const int kb = aq * 8;
        const int kg = k0 + kb;
        float4 x0 = *(const float4*)(arow + kg), x1 = *(const float4*)(arow + kg + 4);
        float4 w0 = *(const float4*)(brow + kg), w1 = *(const float4*)(brow + kg + 4);
        As[kb + 0][am] = x0.x; As[kb + 1][am] = x0.y; As[kb + 2][am] = x0.z; As[kb + 3][am] = x0.w;
        As[kb + 4][am] = x1.x; As[kb + 5][am] = x1.y; As[kb + 6][am] = x1.z; As[kb + 7][am] = x1.w;
        Bs[kb + 0][am] = w0.x; Bs[kb + 1][am] = w0.y; Bs[kb + 2][am] = w0.z; Bs[kb + 3][am] = w0.w;
        Bs[kb + 4][am] = w1.x; Bs[kb + 5][am] = w1.y; Bs[kb + 6][am] = w1.z; Bs[kb + 7][am] = w1.w;
        __syncthreads();
#pragma unroll
        for (int kk = 0; kk < BK; ++kk) {
            float4 a = *(const float4*)&As[kk][tm * 4];
            float4 bb = *(const float4*)&Bs[kk][tn * 4];
            FMA16(a, bb)
        }
        __syncthreads();
    }
    if (tid < BN) { csum[tid] = 0.f; csq[tid] = 0.f; }
    __syncthreads();
    float bvals[4];
    *(float4*)bvals = *(const float4*)(b1 + n0 + tn * 4);
    float colS[4] = {}, colQ[4] = {};
#pragma unroll
    for (int i = 0; i < 4; ++i) {
        int m = m0 + tm * 4 + i;
        float4 r;
        float* rp = &r.x;
#pragma unroll
        for (int j = 0; j < 4; ++j) {
            float zv = fmaxf(acc[i][j] + bvals[j], 0.f);
            rp[j] = zv;
            colS[j] += zv;
            colQ[j] += zv * zv;
        }
        *(float4*)(z1 + (size_t)m * 128 + n0 + tn * 4) = r;
    }
#pragma unroll
    for (int j = 0; j < 4; ++j) {
        atomicAdd(&csum[tn * 4 + j], colS[j]);
        atomicAdd(&csq[tn * 4 + j], colQ[j]);
    }
    __syncthreads();
    if (tid < BN) {
        atomicAdd(&stats[n0 + tid], csum[tid]);
        atomicAdd(&stats[128 + n0 + tid], csq[tid]);
    }
}

// ------------------------------------- layer 2: z2 = relu(BN1(z1)@W2.T + b2)
__global__ __launch_bounds__(256) void k_gemm2(
    const float* __restrict__ z1, float* __restrict__ stats,
    const float* __restrict__ g1, const float* __restrict__ be1,
    const float* __restrict__ W2, const float* __restrict__ b2,
    float* __restrict__ z2) {
    __shared__ float As[BK][BM];
    __shared__ float Bs[BK][BN];
    __shared__ float csum[BN], csq[BN];
    const int tid = threadIdx.x;
    const int m0 = blockIdx.x * BM;
    const int tm = tid >> 4, tn = tid & 15;
    const int am = tid >> 2, aq = tid & 3;
    const float* __restrict__ arow = z1 + (size_t)(m0 + am) * 128;
    const float* __restrict__ brow = W2 + (size_t)am * 128;  // n0 == 0
    const float invB = 1.f / (float)BATCH;
    float acc[4][4] = {};
    for (int k0 = 0; k0 < 128; k0 += BK) {
        const int kb = aq * 8;
        const int kg = k0 + kb;
#pragma unroll
        for (int jj = 0; jj < 8; ++jj) {
            int k = kg + jj;
            float mean = stats[k] * invB;
            float var = stats[128 + k] * invB - mean * mean;
            As[kb + jj][am] = g1[k] * (arow[k] - mean) / sqrtf(var + EPS) + be1[k];
        }
        float4 w0 = *(const float4*)(brow + kg);
        float4 w1 = *(const float4*)(brow + kg + 4);
        Bs[kb + 0][am] = w0.x; Bs[kb + 1][am] = w0.y; Bs[kb + 2][am] = w0.z; Bs[kb + 3][am] = w0.w;
        Bs[kb + 4][am] = w1.x; Bs[kb + 5][am] = w1.y; Bs[kb + 6][am] = w1.z; Bs[kb + 7][am] = w1.w;
        __syncthreads();
#pragma unroll
        for (int kk = 0; kk < BK; ++kk) {
            float4 a = *(const float4*)&As[kk][tm * 4];
            float4 bb = *(const float4*)&Bs[kk][tn * 4];
            FMA16(a, bb)
        }
        __syncthreads();
    }
    if (tid < BN) { csum[tid] = 0.f; csq[tid] = 0.f; }
    __syncthreads();
    float bvals[4];
    *(float4*)bvals = *(const float4*)(b2 + tn * 4);
    float colS[4] = {}, colQ[4] = {};
#pragma unroll
    for (int i = 0; i < 4; ++i) {
        int m = m0 + tm * 4 + i;
        float4 r;
        float* rp = &r.x;
#pragma unroll
        for (int j = 0; j < 4; ++j) {
            float zv = fmaxf(acc[i][j] + bvals[j], 0.f);
            rp[j] = zv;
            colS[j] += zv;
            colQ[j] += zv * zv;
        }
        *(float4*)(z2 + (size_t)m * 64 + tn * 4) = r;
    }
#pragma unroll
    for (int j = 0; j < 4; ++j) {
        atomicAdd(&csum[tn * 4 + j], colS[j]);
        atomicAdd(&csq[tn * 4 + j], colQ[j]);
    }
    __syncthreads();
    if (tid < BN) {
        atomicAdd(&stats[256 + tid], csum[tid]);
        atomicAdd(&stats[320 + tid], csq[tid]);
    }
}

// ------------------------------------------ head: pred = sigmoid(BN2(z2)@Wp.T + bp)
__global__ __launch_bounds__(256) void k_final(
    const float* __restrict__ z2, const float* __restrict__ stats,
    const float* __restrict__ g2, const float* __restrict__ be2,
    const float* __restrict__ Wp, const float* __restrict__ bp,
    float* __restrict__ pred) {
    const int m = blockIdx.x * 4 + (threadIdx.x >> 6);  // one wave per row
    const int lane = threadIdx.x & 63;
    const float invB = 1.f / (float)BATCH;
    float mean = stats[256 + lane] * invB;
    float var = stats[320 + lane] * invB - mean * mean;
    float x = z2[(size_t)m * 64 + lane];
    float f2 = g2[lane] * (x - mean) / sqrtf(var + EPS) + be2[lane];
    float t = f2 * Wp[lane];
#pragma unroll
    for (int off = 32; off > 0; off >>= 1) t += __shfl_down(t, off);
    if (lane == 0) pred[m] = 1.f / (1.f + expf(-(t + bp[0])));
}

// --------------------- final prompt gathers (overwrite z1/z2 scratch regions)
// out_pu = user_prompt[nodes_u], out_pd = domain_prompt[nodes_d].
// Runs last: k_gemm2 (reads z1=out_pu) and k_final (reads z2=out_pd) are done.
__global__ __launch_bounds__(256) void k_gather(
    const int* __restrict__ nodes_u, const int* __restrict__ nodes_d,
    const float* __restrict__ user_prompt, const float* __restrict__ domain_prompt,
    float* __restrict__ out_pu, float* __restrict__ out_pd) {
    int e = blockIdx.x * 256 + threadIdx.x;  // one float4 per thread per output
    int b = e >> 5;
    int c = (e & 31) << 2;
    int u = clampi(nodes_u[b], USER_NUM - 1);
    int dm = clampi(nodes_d[b], DOMAIN_NUM - 1);
    *(float4*)(out_pu + (size_t)b * DIM + c) = *(const float4*)(user_prompt + (size_t)u * DIM + c);
    *(float4*)(out_pd + (size_t)b * DIM + c) = *(const float4*)(domain_prompt + (size_t)dm * DIM + c);
}

extern "C" void kernel_launch(void* const* d_in, const int* in_sizes, int n_in,
                              void* d_out, int out_size, void* d_ws, size_t ws_size,
                              hipStream_t stream) {
    const int* nodes_u       = (const int*)d_in[0];
    const int* nodes_v       = (const int*)d_in[1];
    const int* nodes_d       = (const int*)d_in[2];
    const int* inter_items   = (const int*)d_in[3];
    const int* top_n_index   = (const int*)d_in[4];
    const float* prototypes  = (const float*)d_in[5];
    const float* pre_text    = (const float*)d_in[6];
    const float* pre_visual  = (const float*)d_in[7];
    const float* Wt          = (const float*)d_in[8];
    const float* bt          = (const float*)d_in[9];
    const float* Wv          = (const float*)d_in[10];
    const float* bv          = (const float*)d_in[11];
    const float* user_prompt = (const float*)d_in[12];
    const float* item_prompt = (const float*)d_in[13];
    const float* domain_prompt = (const float*)d_in[14];
    const float* W1          = (const float*)d_in[15];
    const float* b1          = (const float*)d_in[16];
    const float* g1          = (const float*)d_in[17];
    const float* be1         = (const float*)d_in[18];
    const float* W2          = (const float*)d_in[19];
    const float* b2          = (const float*)d_in[20];
    const float* g2          = (const float*)d_in[21];
    const float* be2         = (const float*)d_in[22];
    const float* Wp          = (const float*)d_in[23];
    const float* bp          = (const float*)d_in[24];

    float* ws    = (float*)d_ws;
    float* stats = ws + STATS_OFF;  // 384 floats
    float* inter = ws + INTER_OFF;  // [4096, 256]

    float* pred   = (float*)d_out;                 // [4096]
    float* out_pu = pred + BATCH;                  // [4096,128]
    float* out_hu = out_pu + BATCH * DIM;          // [4096,128]
    float* out_pd = out_hu + BATCH * DIM;          // [4096,128]

    // Scratch aliases inside d_out (rewritten by k_gather at the end):
    float* z1 = out_pu;   // [4096,128] — live k_gemm1 -> k_gemm2
    float* z2 = out_pd;   // [4096,64]  — live k_gemm2 -> k_final

    k_sample<<<BATCH, 128, 0, stream>>>(nodes_d, inter_items, top_n_index,
                                        prototypes, domain_prompt, out_hu, inter);
    k_gemm_e<<<dim3(BATCH / BM, 128 / BN2), 256, 0, stream>>>(
        nodes_v, pre_text, pre_visual, Wt, bt, Wv, bv, item_prompt, inter, stats);
    k_gemm1<<<dim3(BATCH / BM, 128 / BN), 256, 0, stream>>>(inter, W1, b1, z1, stats);
    k_gemm2<<<dim3(BATCH / BM, 1), 256, 0, stream>>>(z1, stats, g1, be1, W2, b2, z2);
    k_final<<<BATCH / 4, 256, 0, stream>>>(z2, stats, g2, be2, Wp, bp, pred);
    k_gather<<<(BATCH * 32) / 256, 256, 0, stream>>>(nodes_u, nodes_d, user_prompt,
                                                     domain_prompt, out_pu, out_pd);
}

// Round 2
// 595.872 us; speedup vs baseline: 1.0569x; 1.0569x over previous
//
#include <hip/hip_runtime.h>
#include <hip/hip_bf16.h>

// Problem constants (from reference)
#define ITEM_NUM 100000
#define PROTO_NUM 1024
#define USER_NUM 100000
#define DOMAIN_NUM 4
#define DIM 128
#define BATCH 4096
#define HIST 50
#define EPS 1e-5f

#define BK 32

// Workspace layout (floats). Total ws use = 384 + 4096*256 floats ≈ 4.2 MB.
// z1 lives in d_out (out_pu, dead after k_gemm2); z2 reuses the inter region
// (dead after k_gemm1). k_final_gather rewrites out_pu/out_pd at the end.
#define STATS_OFF 0            // s1[128], sq1[128], s2[64], sq2[64] = 384
#define INTER_OFF 384          // [4096, 256] (16B-aligned: 384*4 = 1536)

__device__ __forceinline__ int clampi(int v, int hi) {
    return v < 0 ? 0 : (v > hi ? hi : v);
}

// ------------------------------------------------------------- per-sample
// One block per sample b, 128 threads. h_u: 1024-bit presence mask ->
// index list -> vectorized float4 gather (4 row-groups x 32 lanes) ->
// LDS cross-group reduction. Block 0 also zeroes the BN stats accumulators.
__global__ __launch_bounds__(128) void k_sample(
    const int* __restrict__ nodes_d, const int* __restrict__ inter_items,
    const int* __restrict__ top_n_index, const float* __restrict__ prototypes,
    const float* __restrict__ domain_prompt,
    float* __restrict__ out_hu, float* __restrict__ inter_feat,
    float* __restrict__ stats) {
    const int b = blockIdx.x;
    const int d = threadIdx.x;
    __shared__ unsigned int bmask[32];
    __shared__ unsigned short idxlist[400];
    __shared__ float red[4][128];
    if (b == 0) {  // consumed first by k_gemm1 (two launches later)
        stats[d] = 0.f; stats[128 + d] = 0.f; stats[256 + d] = 0.f;
    }
    if (d < 32) bmask[d] = 0u;
    __syncthreads();
    // 100 gather slots: d<50 -> text view, 50<=d<100 -> visual view
    if (d < 2 * HIST) {
        int item = inter_items[b * HIST + (d % HIST)];
        int row = clampi(item + (d >= HIST ? ITEM_NUM : 0), 2 * ITEM_NUM - 1);
        int4 q = *(const int4*)(top_n_index + (size_t)row * 4);
        // JAX scatter drops OOB updates -> skip, don't clamp
        if ((unsigned)q.x < PROTO_NUM) atomicOr(&bmask[((unsigned)q.x) >> 5], 1u << (q.x & 31));
        if ((unsigned)q.y < PROTO_NUM) atomicOr(&bmask[((unsigned)q.y) >> 5], 1u << (q.y & 31));
        if ((unsigned)q.z < PROTO_NUM) atomicOr(&bmask[((unsigned)q.z) >> 5], 1u << (q.z & 31));
        if ((unsigned)q.w < PROTO_NUM) atomicOr(&bmask[((unsigned)q.w) >> 5], 1u << (q.w & 31));
    }
    __syncthreads();
    int cnt = 0;
#pragma unroll
    for (int w = 0; w < 32; ++w) cnt += __popc(bmask[w]);
    if (d < 32) {  // compact set bits into an index list
        int base = 0;
        for (int w = 0; w < d; ++w) base += __popc(bmask[w]);
        unsigned int word = bmask[d];
        while (word) {
            int bit = __ffs(word) - 1;
            word &= word - 1;
            idxlist[base++] = (unsigned short)((d << 5) + bit);
        }
    }
    __syncthreads();
    // Vectorized gather: group g = d>>5 handles rows g, g+4, g+8, ... ;
    // each lane loads one float4 (dims c4..c4+3). One dwordx4 per wave
    // covers two rows (two groups per 64-lane wave).
    const int g = d >> 5;
    const int c4 = (d & 31) << 2;
    float4 a0 = {0.f, 0.f, 0.f, 0.f}, a1 = {0.f, 0.f, 0.f, 0.f};
    int i = g;
    for (; i + 4 < cnt; i += 8) {
        int r0 = idxlist[i], r1 = idxlist[i + 4];
        float4 p0 = *(const float4*)(prototypes + (size_t)r0 * DIM + c4);
        float4 p1 = *(const float4*)(prototypes + (size_t)r1 * DIM + c4);
        a0.x += p0.x; a0.y += p0.y; a0.z += p0.z; a0.w += p0.w;
        a1.x += p1.x; a1.y += p1.y; a1.z += p1.z; a1.w += p1.w;
    }
    for (; i < cnt; i += 4) {
        int r = idxlist[i];
        float4 p = *(const float4*)(prototypes + (size_t)r * DIM + c4);
        a0.x += p.x; a0.y += p.y; a0.z += p.z; a0.w += p.w;
    }
    red[g][c4 + 0] = a0.x + a1.x;
    red[g][c4 + 1] = a0.y + a1.y;
    red[g][c4 + 2] = a0.z + a1.z;
    red[g][c4 + 3] = a0.w + a1.w;
    __syncthreads();
    float hu = ((red[0][d] + red[1][d]) + (red[2][d] + red[3][d])) / (float)cnt;
    int dom = clampi(nodes_d[b], DOMAIN_NUM - 1);
    float pd = domain_prompt[(size_t)dom * DIM + d];
    out_hu[(size_t)b * DIM + d] = hu;
    inter_feat[(size_t)b * 256 + d] = hu + pd;  // h_u_hat
}

// ----------------------------------------------- gathered-row e-feature GEMM
// inter_feat[:,128:256] = (xcat(nodes_v) - bcat) @ Wcat.T + item_prompt[nodes_v]
// xcat = [pre_text row (384) | pre_visual row (768)], K = 1152.
// 32x32 tiles -> grid(128,4) = 512 blocks (2/CU, 8 waves/CU).
__global__ __launch_bounds__(256) void k_gemm_e(
    const int* __restrict__ nodes_v,
    const float* __restrict__ pre_text, const float* __restrict__ pre_visual,
    const float* __restrict__ Wt, const float* __restrict__ bt,
    const float* __restrict__ Wv, const float* __restrict__ bv,
    const float* __restrict__ item_prompt, float* __restrict__ inter_feat) {
    __shared__ float As[BK][34];   // +2 pad: conflict-light, keeps 8B align
    __shared__ float Bs[BK][34];
    const int tid = threadIdx.x;
    const int m0 = blockIdx.x * 32;
    const int n0 = blockIdx.y * 32;
    const int am = tid >> 3, aq = tid & 7;
    const int kb = aq * 4;
    const int arow = clampi(nodes_v[m0 + am], ITEM_NUM - 1);
    const float* __restrict__ at = pre_text + (size_t)arow * 384;
    const float* __restrict__ av = pre_visual + (size_t)arow * 768;
    const float* __restrict__ wt = Wt + (size_t)(n0 + am) * 384;
    const float* __restrict__ wv = Wv + (size_t)(n0 + am) * 768;
    const int tm = tid >> 4, tn = tid & 15;
    float acc[2][2] = {};
    for (int k0 = 0; k0 < 1152; k0 += BK) {
        const int kg = k0 + kb;     // branch uniform per block (384 % 32 == 0)
        float4 x, c, w;
        if (kg < 384) {
            x = *(const float4*)(at + kg); c = *(const float4*)(bt + kg);
            w = *(const float4*)(wt + kg);
        } else {
            int kh = kg - 384;
            x = *(const float4*)(av + kh); c = *(const float4*)(bv + kh);
            w = *(const float4*)(wv + kh);
        }
        As[kb + 0][am] = x.x - c.x; As[kb + 1][am] = x.y - c.y;
        As[kb + 2][am] = x.z - c.z; As[kb + 3][am] = x.w - c.w;
        Bs[kb + 0][am] = w.x; Bs[kb + 1][am] = w.y;
        Bs[kb + 2][am] = w.z; Bs[kb + 3][am] = w.w;
        __syncthreads();
#pragma unroll
        for (int kk = 0; kk < BK; ++kk) {
            float2 a = *(const float2*)&As[kk][tm * 2];
            float2 bb = *(const float2*)&Bs[kk][tn * 2];
            acc[0][0] += a.x * bb.x; acc[0][1] += a.x * bb.y;
            acc[1][0] += a.y * bb.x; acc[1][1] += a.y * bb.y;
        }
        __syncthreads();
    }
#pragma unroll
    for (int i = 0; i < 2; ++i) {
        int m = m0 + tm * 2 + i;
        int v = clampi(nodes_v[m], ITEM_NUM - 1);
        const float* __restrict__ ip = item_prompt + (size_t)v * DIM + n0 + tn * 2;
        float2 r;
        r.x = acc[i][0] + ip[0];
        r.y = acc[i][1] + ip[1];
        *(float2*)(inter_feat + (size_t)m * 256 + 128 + n0 + tn * 2) = r;
    }
}

// --------------------------------------------------- layer 1: z1 = relu(inter@W1.T + b1)
// 32x64 tiles -> grid(128,2) = 256 blocks (full GPU).
__global__ __launch_bounds__(256) void k_gemm1(
    const float* __restrict__ inter_feat, const float* __restrict__ W1,
    const float* __restrict__ b1, float* __restrict__ z1, float* __restrict__ stats) {
    __shared__ float As[BK][34];
    __shared__ float Bs[BK][68];   // +4 pad keeps 16B alignment for b128 reads
    __shared__ float csum[64], csq[64];
    const int tid = threadIdx.x;
    const int m0 = blockIdx.x * 32;
    const int n0 = blockIdx.y * 64;
    const int am = tid >> 3, aq = tid & 7;
    const int kb = aq * 4;
    const float* __restrict__ arow = inter_feat + (size_t)(m0 + am) * 256;
    const float* __restrict__ br0 = W1 + (size_t)(n0 + am) * 256;
    const float* __restrict__ br1 = W1 + (size_t)(n0 + am + 32) * 256;
    const int tm = tid >> 4, tn = tid & 15;
    float acc[2][4] = {};
    for (int k0 = 0; k0 < 256; k0 += BK) {
        const int kg = k0 + kb;
        float4 x  = *(const float4*)(arow + kg);
        float4 w0 = *(const float4*)(br0 + kg);
        float4 w1 = *(const float4*)(br1 + kg);
        As[kb + 0][am] = x.x; As[kb + 1][am] = x.y; As[kb + 2][am] = x.z; As[kb + 3][am] = x.w;
        Bs[kb + 0][am] = w0.x; Bs[kb + 1][am] = w0.y; Bs[kb + 2][am] = w0.z; Bs[kb + 3][am] = w0.w;
        Bs[kb + 0][am + 32] = w1.x; Bs[kb + 1][am + 32] = w1.y;
        Bs[kb + 2][am + 32] = w1.z; Bs[kb + 3][am + 32] = w1.w;
        __syncthreads();
#pragma unroll
        for (int kk = 0; kk < BK; ++kk) {
            float2 a = *(const float2*)&As[kk][tm * 2];
            float4 bb = *(const float4*)&Bs[kk][tn * 4];
            acc[0][0] += a.x * bb.x; acc[0][1] += a.x * bb.y;
            acc[0][2] += a.x * bb.z; acc[0][3] += a.x * bb.w;
            acc[1][0] += a.y * bb.x; acc[1][1] += a.y * bb.y;
            acc[1][2] += a.y * bb.z; acc[1][3] += a.y * bb.w;
        }
        __syncthreads();
    }
    if (tid < 64) { csum[tid] = 0.f; csq[tid] = 0.f; }
    __syncthreads();
    float bvals[4];
    *(float4*)bvals = *(const float4*)(b1 + n0 + tn * 4);
    float colS[4] = {}, colQ[4] = {};
#pragma unroll
    for (int i = 0; i < 2; ++i) {
        int m = m0 + tm * 2 + i;
        float4 r;
        float* rp = &r.x;
#pragma unroll
        for (int j = 0; j < 4; ++j) {
            float zv = fmaxf(acc[i][j] + bvals[j], 0.f);
            rp[j] = zv;
            colS[j] += zv;
            colQ[j] += zv * zv;
        }
        *(float4*)(z1 + (size_t)m * 128 + n0 + tn * 4) = r;
    }
#pragma unroll
    for (int j = 0; j < 4; ++j) {
        atomicAdd(&csum[tn * 4 + j], colS[j]);
        atomicAdd(&csq[tn * 4 + j], colQ[j]);
    }
    __syncthreads();
    if (tid < 64) {
        atomicAdd(&stats[n0 + tid], csum[tid]);
        atomicAdd(&stats[128 + n0 + tid], csq[tid]);
    }
}

// ------------------------------------- layer 2: z2 = relu(BN1(z1)@W2.T + b2)
// 16x64 tiles -> 256 blocks (full GPU).
__global__ __launch_bounds__(256) void k_gemm2(
    const float* __restrict__ z1, float* __restrict__ stats,
    const float* __restrict__ g1, const float* __restrict__ be1,
    const float* __restrict__ W2, const float* __restrict__ b2,
    float* __restrict__ z2) {
    __shared__ float As[BK][18];
    __shared__ float Bs[BK][68];
    __shared__ float csum[64], csq[64];
    const int tid = threadIdx.x;
    const int m0 = blockIdx.x * 16;
    const int am = tid >> 3, aq = tid & 7;
    const int kb = aq * 4;
    const float* __restrict__ br0 = W2 + (size_t)am * 128;
    const float* __restrict__ br1 = W2 + (size_t)(am + 32) * 128;
    const int tr = tid >> 4, tn = tid & 15;
    const float invB = 1.f / (float)BATCH;
    float acc[4] = {};
    for (int k0 = 0; k0 < 128; k0 += BK) {
        const int kg = k0 + kb;
        if (tid < 128) {  // A stage: 16 rows x 32 k, BN1-normalized
            const int am2 = tid >> 3;
            const float* __restrict__ arow = z1 + (size_t)(m0 + am2) * 128;
            float4 x = *(const float4*)(arow + kg);
            float* xp = &x.x;
#pragma unroll
            for (int j = 0; j < 4; ++j) {
                int k = kg + j;
                float mean = stats[k] * invB;
                float var = stats[128 + k] * invB - mean * mean;
                As[kb + j][am2] = g1[k] * (xp[j] - mean) / sqrtf(var + EPS) + be1[k];
            }
        }
        float4 w0 = *(const float4*)(br0 + kg);
        float4 w1 = *(const float4*)(br1 + kg);
        Bs[kb + 0][am] = w0.x; Bs[kb + 1][am] = w0.y; Bs[kb + 2][am] = w0.z; Bs[kb + 3][am] = w0.w;
        Bs[kb + 0][am + 32] = w1.x; Bs[kb + 1][am + 32] = w1.y;
        Bs[kb + 2][am + 32] = w1.z; Bs[kb + 3][am + 32] = w1.w;
        __syncthreads();
#pragma unroll
        for (int kk = 0; kk < BK; ++kk) {
            float a = As[kk][tr];
            float4 bb = *(const float4*)&Bs[kk][tn * 4];
            acc[0] += a * bb.x; acc[1] += a * bb.y;
            acc[2] += a * bb.z; acc[3] += a * bb.w;
        }
        __syncthreads();
    }
    if (tid < 64) { csum[tid] = 0.f; csq[tid] = 0.f; }
    __syncthreads();
    float bvals[4];
    *(float4*)bvals = *(const float4*)(b2 + tn * 4);
    float colS[4] = {}, colQ[4] = {};
    {
        int m = m0 + tr;
        float4 r;
        float* rp = &r.x;
#pragma unroll
        for (int j = 0; j < 4; ++j) {
            float zv = fmaxf(acc[j] + bvals[j], 0.f);
            rp[j] = zv;
            colS[j] += zv;
            colQ[j] += zv * zv;
        }
        *(float4*)(z2 + (size_t)m * 64 + tn * 4) = r;
    }
#pragma unroll
    for (int j = 0; j < 4; ++j) {
        atomicAdd(&csum[tn * 4 + j], colS[j]);
        atomicAdd(&csq[tn * 4 + j], colQ[j]);
    }
    __syncthreads();
    if (tid < 64) {
        atomicAdd(&stats[256 + tid], csum[tid]);
        atomicAdd(&stats[320 + tid], csq[tid]);
    }
}

// ---------------- head + prompt gathers: pred = sigmoid(BN2(z2)@Wp.T + bp),
// out_pu = user_prompt[nodes_u], out_pd = domain_prompt[nodes_d].
// z2 lives in ws (no alias with out_pd), so no ordering hazard here.
__global__ __launch_bounds__(256) void k_final_gather(
    const float* __restrict__ z2, const float* __restrict__ stats,
    const float* __restrict__ g2, const float* __restrict__ be2,
    const float* __restrict__ Wp, const float* __restrict__ bp,
    const int* __restrict__ nodes_u, const int* __restrict__ nodes_d,
    const float* __restrict__ user_prompt, const float* __restrict__ domain_prompt,
    float* __restrict__ pred, float* __restrict__ out_pu, float* __restrict__ out_pd) {
    const int w = threadIdx.x >> 6;          // wave = one sample
    const int lane = threadIdx.x & 63;
    const int m = blockIdx.x * 4 + w;
    const float invB = 1.f / (float)BATCH;
    float mean = stats[256 + lane] * invB;
    float var = stats[320 + lane] * invB - mean * mean;
    float x = z2[(size_t)m * 64 + lane];
    float f2 = g2[lane] * (x - mean) / sqrtf(var + EPS) + be2[lane];
    float t = f2 * Wp[lane];
#pragma unroll
    for (int off = 32; off > 0; off >>= 1) t += __shfl_down(t, off);
    if (lane == 0) pred[m] = 1.f / (1.f + expf(-(t + bp[0])));
    // prompt gathers: lane<32 -> one float4 of out_pu, lane>=32 -> out_pd
    if (lane < 32) {
        int u = clampi(nodes_u[m], USER_NUM - 1);
        *(float4*)(out_pu + (size_t)m * DIM + lane * 4) =
            *(const float4*)(user_prompt + (size_t)u * DIM + lane * 4);
    } else {
        int dm = clampi(nodes_d[m], DOMAIN_NUM - 1);
        int c = (lane - 32) * 4;
        *(float4*)(out_pd + (size_t)m * DIM + c) =
            *(const float4*)(domain_prompt + (size_t)dm * DIM + c);
    }
}

extern "C" void kernel_launch(void* const* d_in, const int* in_sizes, int n_in,
                              void* d_out, int out_size, void* d_ws, size_t ws_size,
                              hipStream_t stream) {
    const int* nodes_u       = (const int*)d_in[0];
    const int* nodes_v       = (const int*)d_in[1];
    const int* nodes_d       = (const int*)d_in[2];
    const int* inter_items   = (const int*)d_in[3];
    const int* top_n_index   = (const int*)d_in[4];
    const float* prototypes  = (const float*)d_in[5];
    const float* pre_text    = (const float*)d_in[6];
    const float* pre_visual  = (const float*)d_in[7];
    const float* Wt          = (const float*)d_in[8];
    const float* bt          = (const float*)d_in[9];
    const float* Wv          = (const float*)d_in[10];
    const float* bv          = (const float*)d_in[11];
    const float* user_prompt = (const float*)d_in[12];
    const float* item_prompt = (const float*)d_in[13];
    const float* domain_prompt = (const float*)d_in[14];
    const float* W1          = (const float*)d_in[15];
    const float* b1          = (const float*)d_in[16];
    const float* g1          = (const float*)d_in[17];
    const float* be1         = (const float*)d_in[18];
    const float* W2          = (const float*)d_in[19];
    const float* b2          = (const float*)d_in[20];
    const float* g2          = (const float*)d_in[21];
    const float* be2         = (const float*)d_in[22];
    const float* Wp          = (const float*)d_in[23];
    const float* bp          = (const float*)d_in[24];

    float* ws    = (float*)d_ws;
    float* stats = ws + STATS_OFF;  // 384 floats
    float* inter = ws + INTER_OFF;  // [4096, 256]

    float* pred   = (float*)d_out;                 // [4096]
    float* out_pu = pred + BATCH;                  // [4096,128]
    float* out_hu = out_pu + BATCH * DIM;          // [4096,128]
    float* out_pd = out_hu + BATCH * DIM;          // [4096,128]

    // Scratch aliases (all rewritten before final consumers):
    float* z1 = out_pu;   // [4096,128] — live k_gemm1 -> k_gemm2; rewritten by k_final_gather
    float* z2 = inter;    // [4096,64]  — reuses inter (dead after k_gemm1)

    k_sample<<<BATCH, 128, 0, stream>>>(nodes_d, inter_items, top_n_index,
                                        prototypes, domain_prompt, out_hu, inter, stats);
    k_gemm_e<<<dim3(BATCH / 32, 128 / 32), 256, 0, stream>>>(
        nodes_v, pre_text, pre_visual, Wt, bt, Wv, bv, item_prompt, inter);
    k_gemm1<<<dim3(BATCH / 32, 128 / 64), 256, 0, stream>>>(inter, W1, b1, z1, stats);
    k_gemm2<<<BATCH / 16, 256, 0, stream>>>(z1, stats, g1, be1, W2, b2, z2);
    k_final_gather<<<BATCH / 4, 256, 0, stream>>>(z2, stats, g2, be2, Wp, bp,
                                                  nodes_u, nodes_d, user_prompt,
                                                  domain_prompt, pred, out_pu, out_pd);
}

// Round 3
// 571.667 us; speedup vs baseline: 1.1017x; 1.0423x over previous
//
#include <hip/hip_runtime.h>
#include <hip/hip_bf16.h>

// Problem constants (from reference)
#define ITEM_NUM 100000
#define PROTO_NUM 1024
#define USER_NUM 100000
#define DOMAIN_NUM 4
#define DIM 128
#define BATCH 4096
#define HIST 50
#define EPS 1e-5f

#define BK 32

// Workspace layout (floats). Total ws use = 384 + 4096*256 floats ≈ 4.2 MB.
// z1 lives in d_out (out_pu, dead after k_gemm2); z2 reuses the inter region
// (dead after k_gemm1). k_final_gather rewrites out_pu/out_pd at the end.
#define STATS_OFF 0            // s1[128], sq1[128], s2[64], sq2[64] = 384
#define INTER_OFF 384          // [4096, 256] (16B-aligned: 384*4 = 1536)

// k_front grid split: blocks [0, EBLK) do the e-feature GEMM, blocks
// [EBLK, EBLK + BATCH/2) do per-sample h_u work (2 samples per block).
#define EBLK 512

__device__ __forceinline__ int clampi(int v, int hi) {
    return v < 0 ? 0 : (v > hi ? hi : v);
}

// ------------------------------------------------------------- front kernel
// Fuses the two independent producers of inter_feat:
//  * e-part (blocks 0..511): inter[:,128:256] = (xcat - bcat)@Wcat.T + p_v
//    (32x32 tiles, K=1152 over [pre_text|pre_visual])
//  * sample-part (blocks 512..2559): h_u via presence-mask gather; 2 samples
//    per 256-thread block. inter[:,0:128] = h_u + p_d.
// gemm_e blocks come FIRST so their compute overlaps the latency-bound
// sample gather instead of serializing after it.
__global__ __launch_bounds__(256) void k_front(
    const int* __restrict__ nodes_v, const int* __restrict__ nodes_d,
    const int* __restrict__ inter_items, const int* __restrict__ top_n_index,
    const float* __restrict__ prototypes,
    const float* __restrict__ pre_text, const float* __restrict__ pre_visual,
    const float* __restrict__ Wt, const float* __restrict__ bt,
    const float* __restrict__ Wv, const float* __restrict__ bv,
    const float* __restrict__ item_prompt, const float* __restrict__ domain_prompt,
    float* __restrict__ out_hu, float* __restrict__ inter_feat,
    float* __restrict__ stats) {
    __shared__ float As[BK][34];
    __shared__ float Bs[BK][34];
    __shared__ unsigned int bmask[2][32];
    __shared__ unsigned short idxlist[2][400];
    __shared__ float red[2][4][128];
    const int tid = threadIdx.x;

    if (blockIdx.x < EBLK) {
        // ---------------- e-feature GEMM part ----------------
        if (blockIdx.x == 0 && tid < 128) {  // stats consumed first by k_gemm1
            stats[tid] = 0.f; stats[128 + tid] = 0.f; stats[256 + tid] = 0.f;
        }
        const int m0 = (blockIdx.x >> 2) * 32;
        const int n0 = (blockIdx.x & 3) * 32;
        const int am = tid >> 3, aq = tid & 7;
        const int kb = aq * 4;
        const int arow = clampi(nodes_v[m0 + am], ITEM_NUM - 1);
        const float* __restrict__ at = pre_text + (size_t)arow * 384;
        const float* __restrict__ av = pre_visual + (size_t)arow * 768;
        const float* __restrict__ wt = Wt + (size_t)(n0 + am) * 384;
        const float* __restrict__ wv = Wv + (size_t)(n0 + am) * 768;
        const int tm = tid >> 4, tn = tid & 15;
        float acc[2][2] = {};
        for (int k0 = 0; k0 < 1152; k0 += BK) {
            const int kg = k0 + kb;     // branch uniform per block (384 % 32 == 0)
            float4 x, c, w;
            if (kg < 384) {
                x = *(const float4*)(at + kg); c = *(const float4*)(bt + kg);
                w = *(const float4*)(wt + kg);
            } else {
                int kh = kg - 384;
                x = *(const float4*)(av + kh); c = *(const float4*)(bv + kh);
                w = *(const float4*)(wv + kh);
            }
            As[kb + 0][am] = x.x - c.x; As[kb + 1][am] = x.y - c.y;
            As[kb + 2][am] = x.z - c.z; As[kb + 3][am] = x.w - c.w;
            Bs[kb + 0][am] = w.x; Bs[kb + 1][am] = w.y;
            Bs[kb + 2][am] = w.z; Bs[kb + 3][am] = w.w;
            __syncthreads();
#pragma unroll
            for (int kk = 0; kk < BK; ++kk) {
                float2 a = *(const float2*)&As[kk][tm * 2];
                float2 bb = *(const float2*)&Bs[kk][tn * 2];
                acc[0][0] += a.x * bb.x; acc[0][1] += a.x * bb.y;
                acc[1][0] += a.y * bb.x; acc[1][1] += a.y * bb.y;
            }
            __syncthreads();
        }
#pragma unroll
        for (int i = 0; i < 2; ++i) {
            int m = m0 + tm * 2 + i;
            int v = clampi(nodes_v[m], ITEM_NUM - 1);
            const float* __restrict__ ip = item_prompt + (size_t)v * DIM + n0 + tn * 2;
            float2 r;
            r.x = acc[i][0] + ip[0];
            r.y = acc[i][1] + ip[1];
            *(float2*)(inter_feat + (size_t)m * 256 + 128 + n0 + tn * 2) = r;
        }
    } else {
        // ---------------- per-sample h_u part (2 samples/block) ----------------
        const int u = tid >> 7;        // sample unit 0/1 within block
        const int d = tid & 127;
        const int b = (blockIdx.x - EBLK) * 2 + u;
        if (d < 32) bmask[u][d] = 0u;
        __syncthreads();
        // 100 gather slots: d<50 -> text view, 50<=d<100 -> visual view
        if (d < 2 * HIST) {
            int item = inter_items[b * HIST + (d % HIST)];
            int row = clampi(item + (d >= HIST ? ITEM_NUM : 0), 2 * ITEM_NUM - 1);
            int4 q = *(const int4*)(top_n_index + (size_t)row * 4);
            // JAX scatter drops OOB updates -> skip, don't clamp
            if ((unsigned)q.x < PROTO_NUM) atomicOr(&bmask[u][((unsigned)q.x) >> 5], 1u << (q.x & 31));
            if ((unsigned)q.y < PROTO_NUM) atomicOr(&bmask[u][((unsigned)q.y) >> 5], 1u << (q.y & 31));
            if ((unsigned)q.z < PROTO_NUM) atomicOr(&bmask[u][((unsigned)q.z) >> 5], 1u << (q.z & 31));
            if ((unsigned)q.w < PROTO_NUM) atomicOr(&bmask[u][((unsigned)q.w) >> 5], 1u << (q.w & 31));
        }
        __syncthreads();
        int cnt = 0;
#pragma unroll
        for (int w = 0; w < 32; ++w) cnt += __popc(bmask[u][w]);
        if (d < 32) {  // compact set bits into an index list
            int base = 0;
            for (int w = 0; w < d; ++w) base += __popc(bmask[u][w]);
            unsigned int word = bmask[u][d];
            while (word) {
                int bit = __ffs(word) - 1;
                word &= word - 1;
                idxlist[u][base++] = (unsigned short)((d << 5) + bit);
            }
        }
        __syncthreads();
        // Vectorized gather: group g = d>>5 handles rows g, g+4, g+8, ...;
        // each lane loads one float4 (dims c4..c4+3). 4 independent load
        // streams per group for memory-level parallelism.
        const int g = d >> 5;
        const int c4 = (d & 31) << 2;
        float4 a0 = {0.f, 0.f, 0.f, 0.f}, a1 = {0.f, 0.f, 0.f, 0.f};
        float4 a2 = {0.f, 0.f, 0.f, 0.f}, a3 = {0.f, 0.f, 0.f, 0.f};
        int i = g;
        for (; i + 12 < cnt; i += 16) {
            int r0 = idxlist[u][i],     r1 = idxlist[u][i + 4];
            int r2 = idxlist[u][i + 8], r3 = idxlist[u][i + 12];
            float4 p0 = *(const float4*)(prototypes + (size_t)r0 * DIM + c4);
            float4 p1 = *(const float4*)(prototypes + (size_t)r1 * DIM + c4);
            float4 p2 = *(const float4*)(prototypes + (size_t)r2 * DIM + c4);
            float4 p3 = *(const float4*)(prototypes + (size_t)r3 * DIM + c4);
            a0.x += p0.x; a0.y += p0.y; a0.z += p0.z; a0.w += p0.w;
            a1.x += p1.x; a1.y += p1.y; a1.z += p1.z; a1.w += p1.w;
            a2.x += p2.x; a2.y += p2.y; a2.z += p2.z; a2.w += p2.w;
            a3.x += p3.x; a3.y += p3.y; a3.z += p3.z; a3.w += p3.w;
        }
        for (; i < cnt; i += 4) {
            int r = idxlist[u][i];
            float4 p = *(const float4*)(prototypes + (size_t)r * DIM + c4);
            a0.x += p.x; a0.y += p.y; a0.z += p.z; a0.w += p.w;
        }
        red[u][g][c4 + 0] = (a0.x + a1.x) + (a2.x + a3.x);
        red[u][g][c4 + 1] = (a0.y + a1.y) + (a2.y + a3.y);
        red[u][g][c4 + 2] = (a0.z + a1.z) + (a2.z + a3.z);
        red[u][g][c4 + 3] = (a0.w + a1.w) + (a2.w + a3.w);
        __syncthreads();
        float hu = ((red[u][0][d] + red[u][1][d]) + (red[u][2][d] + red[u][3][d])) / (float)cnt;
        int dom = clampi(nodes_d[b], DOMAIN_NUM - 1);
        float pd = domain_prompt[(size_t)dom * DIM + d];
        out_hu[(size_t)b * DIM + d] = hu;
        inter_feat[(size_t)b * 256 + d] = hu + pd;  // h_u_hat
    }
}

// --------------------------------------------------- layer 1: z1 = relu(inter@W1.T + b1)
// 32x64 tiles -> grid(128,2) = 256 blocks (full GPU).
__global__ __launch_bounds__(256) void k_gemm1(
    const float* __restrict__ inter_feat, const float* __restrict__ W1,
    const float* __restrict__ b1, float* __restrict__ z1, float* __restrict__ stats) {
    __shared__ float As[BK][34];
    __shared__ float Bs[BK][68];   // +4 pad keeps 16B alignment for b128 reads
    __shared__ float csum[64], csq[64];
    const int tid = threadIdx.x;
    const int m0 = blockIdx.x * 32;
    const int n0 = blockIdx.y * 64;
    const int am = tid >> 3, aq = tid & 7;
    const int kb = aq * 4;
    const float* __restrict__ arow = inter_feat + (size_t)(m0 + am) * 256;
    const float* __restrict__ br0 = W1 + (size_t)(n0 + am) * 256;
    const float* __restrict__ br1 = W1 + (size_t)(n0 + am + 32) * 256;
    const int tm = tid >> 4, tn = tid & 15;
    float acc[2][4] = {};
    for (int k0 = 0; k0 < 256; k0 += BK) {
        const int kg = k0 + kb;
        float4 x  = *(const float4*)(arow + kg);
        float4 w0 = *(const float4*)(br0 + kg);
        float4 w1 = *(const float4*)(br1 + kg);
        As[kb + 0][am] = x.x; As[kb + 1][am] = x.y; As[kb + 2][am] = x.z; As[kb + 3][am] = x.w;
        Bs[kb + 0][am] = w0.x; Bs[kb + 1][am] = w0.y; Bs[kb + 2][am] = w0.z; Bs[kb + 3][am] = w0.w;
        Bs[kb + 0][am + 32] = w1.x; Bs[kb + 1][am + 32] = w1.y;
        Bs[kb + 2][am + 32] = w1.z; Bs[kb + 3][am + 32] = w1.w;
        __syncthreads();
#pragma unroll
        for (int kk = 0; kk < BK; ++kk) {
            float2 a = *(const float2*)&As[kk][tm * 2];
            float4 bb = *(const float4*)&Bs[kk][tn * 4];
            acc[0][0] += a.x * bb.x; acc[0][1] += a.x * bb.y;
            acc[0][2] += a.x * bb.z; acc[0][3] += a.x * bb.w;
            acc[1][0] += a.y * bb.x; acc[1][1] += a.y * bb.y;
            acc[1][2] += a.y * bb.z; acc[1][3] += a.y * bb.w;
        }
        __syncthreads();
    }
    if (tid < 64) { csum[tid] = 0.f; csq[tid] = 0.f; }
    __syncthreads();
    float bvals[4];
    *(float4*)bvals = *(const float4*)(b1 + n0 + tn * 4);
    float colS[4] = {}, colQ[4] = {};
#pragma unroll
    for (int i = 0; i < 2; ++i) {
        int m = m0 + tm * 2 + i;
        float4 r;
        float* rp = &r.x;
#pragma unroll
        for (int j = 0; j < 4; ++j) {
            float zv = fmaxf(acc[i][j] + bvals[j], 0.f);
            rp[j] = zv;
            colS[j] += zv;
            colQ[j] += zv * zv;
        }
        *(float4*)(z1 + (size_t)m * 128 + n0 + tn * 4) = r;
    }
#pragma unroll
    for (int j = 0; j < 4; ++j) {
        atomicAdd(&csum[tn * 4 + j], colS[j]);
        atomicAdd(&csq[tn * 4 + j], colQ[j]);
    }
    __syncthreads();
    if (tid < 64) {
        atomicAdd(&stats[n0 + tid], csum[tid]);
        atomicAdd(&stats[128 + n0 + tid], csq[tid]);
    }
}

// ------------------------------------- layer 2: z2 = relu(BN1(z1)@W2.T + b2)
// 16x64 tiles -> 256 blocks (full GPU).
__global__ __launch_bounds__(256) void k_gemm2(
    const float* __restrict__ z1, float* __restrict__ stats,
    const float* __restrict__ g1, const float* __restrict__ be1,
    const float* __restrict__ W2, const float* __restrict__ b2,
    float* __restrict__ z2) {
    __shared__ float As[BK][18];
    __shared__ float Bs[BK][68];
    __shared__ float csum[64], csq[64];
    const int tid = threadIdx.x;
    const int m0 = blockIdx.x * 16;
    const int am = tid >> 3, aq = tid & 7;
    const int kb = aq * 4;
    const float* __restrict__ br0 = W2 + (size_t)am * 128;
    const float* __restrict__ br1 = W2 + (size_t)(am + 32) * 128;
    const int tr = tid >> 4, tn = tid & 15;
    const float invB = 1.f / (float)BATCH;
    float acc[4] = {};
    for (int k0 = 0; k0 < 128; k0 += BK) {
        const int kg = k0 + kb;
        if (tid < 128) {  // A stage: 16 rows x 32 k, BN1-normalized
            const int am2 = tid >> 3;
            const float* __restrict__ arow = z1 + (size_t)(m0 + am2) * 128;
            float4 x = *(const float4*)(arow + kg);
            float* xp = &x.x;
#pragma unroll
            for (int j = 0; j < 4; ++j) {
                int k = kg + j;
                float mean = stats[k] * invB;
                float var = stats[128 + k] * invB - mean * mean;
                As[kb + j][am2] = g1[k] * (xp[j] - mean) / sqrtf(var + EPS) + be1[k];
            }
        }
        float4 w0 = *(const float4*)(br0 + kg);
        float4 w1 = *(const float4*)(br1 + kg);
        Bs[kb + 0][am] = w0.x; Bs[kb + 1][am] = w0.y; Bs[kb + 2][am] = w0.z; Bs[kb + 3][am] = w0.w;
        Bs[kb + 0][am + 32] = w1.x; Bs[kb + 1][am + 32] = w1.y;
        Bs[kb + 2][am + 32] = w1.z; Bs[kb + 3][am + 32] = w1.w;
        __syncthreads();
#pragma unroll
        for (int kk = 0; kk < BK; ++kk) {
            float a = As[kk][tr];
            float4 bb = *(const float4*)&Bs[kk][tn * 4];
            acc[0] += a * bb.x; acc[1] += a * bb.y;
            acc[2] += a * bb.z; acc[3] += a * bb.w;
        }
        __syncthreads();
    }
    if (tid < 64) { csum[tid] = 0.f; csq[tid] = 0.f; }
    __syncthreads();
    float bvals[4];
    *(float4*)bvals = *(const float4*)(b2 + tn * 4);
    float colS[4] = {}, colQ[4] = {};
    {
        int m = m0 + tr;
        float4 r;
        float* rp = &r.x;
#pragma unroll
        for (int j = 0; j < 4; ++j) {
            float zv = fmaxf(acc[j] + bvals[j], 0.f);
            rp[j] = zv;
            colS[j] += zv;
            colQ[j] += zv * zv;
        }
        *(float4*)(z2 + (size_t)m * 64 + tn * 4) = r;
    }
#pragma unroll
    for (int j = 0; j < 4; ++j) {
        atomicAdd(&csum[tn * 4 + j], colS[j]);
        atomicAdd(&csq[tn * 4 + j], colQ[j]);
    }
    __syncthreads();
    if (tid < 64) {
        atomicAdd(&stats[256 + tid], csum[tid]);
        atomicAdd(&stats[320 + tid], csq[tid]);
    }
}

// ---------------- head + prompt gathers: pred = sigmoid(BN2(z2)@Wp.T + bp),
// out_pu = user_prompt[nodes_u], out_pd = domain_prompt[nodes_d].
// z2 lives in ws (no alias with out_pd), so no ordering hazard here.
__global__ __launch_bounds__(256) void k_final_gather(
    const float* __restrict__ z2, const float* __restrict__ stats,
    const float* __restrict__ g2, const float* __restrict__ be2,
    const float* __restrict__ Wp, const float* __restrict__ bp,
    const int* __restrict__ nodes_u, const int* __restrict__ nodes_d,
    const float* __restrict__ user_prompt, const float* __restrict__ domain_prompt,
    float* __restrict__ pred, float* __restrict__ out_pu, float* __restrict__ out_pd) {
    const int w = threadIdx.x >> 6;          // wave = one sample
    const int lane = threadIdx.x & 63;
    const int m = blockIdx.x * 4 + w;
    const float invB = 1.f / (float)BATCH;
    float mean = stats[256 + lane] * invB;
    float var = stats[320 + lane] * invB - mean * mean;
    float x = z2[(size_t)m * 64 + lane];
    float f2 = g2[lane] * (x - mean) / sqrtf(var + EPS) + be2[lane];
    float t = f2 * Wp[lane];
#pragma unroll
    for (int off = 32; off > 0; off >>= 1) t += __shfl_down(t, off);
    if (lane == 0) pred[m] = 1.f / (1.f + expf(-(t + bp[0])));
    // prompt gathers: lane<32 -> one float4 of out_pu, lane>=32 -> out_pd
    if (lane < 32) {
        int u = clampi(nodes_u[m], USER_NUM - 1);
        *(float4*)(out_pu + (size_t)m * DIM + lane * 4) =
            *(const float4*)(user_prompt + (size_t)u * DIM + lane * 4);
    } else {
        int dm = clampi(nodes_d[m], DOMAIN_NUM - 1);
        int c = (lane - 32) * 4;
        *(float4*)(out_pd + (size_t)m * DIM + c) =
            *(const float4*)(domain_prompt + (size_t)dm * DIM + c);
    }
}

extern "C" void kernel_launch(void* const* d_in, const int* in_sizes, int n_in,
                              void* d_out, int out_size, void* d_ws, size_t ws_size,
                              hipStream_t stream) {
    const int* nodes_u       = (const int*)d_in[0];
    const int* nodes_v       = (const int*)d_in[1];
    const int* nodes_d       = (const int*)d_in[2];
    const int* inter_items   = (const int*)d_in[3];
    const int* top_n_index   = (const int*)d_in[4];
    const float* prototypes  = (const float*)d_in[5];
    const float* pre_text    = (const float*)d_in[6];
    const float* pre_visual  = (const float*)d_in[7];
    const float* Wt          = (const float*)d_in[8];
    const float* bt          = (const float*)d_in[9];
    const float* Wv          = (const float*)d_in[10];
    const float* bv          = (const float*)d_in[11];
    const float* user_prompt = (const float*)d_in[12];
    const float* item_prompt = (const float*)d_in[13];
    const float* domain_prompt = (const float*)d_in[14];
    const float* W1          = (const float*)d_in[15];
    const float* b1          = (const float*)d_in[16];
    const float* g1          = (const float*)d_in[17];
    const float* be1         = (const float*)d_in[18];
    const float* W2          = (const float*)d_in[19];
    const float* b2          = (const float*)d_in[20];
    const float* g2          = (const float*)d_in[21];
    const float* be2         = (const float*)d_in[22];
    const float* Wp          = (const float*)d_in[23];
    const float* bp          = (const float*)d_in[24];

    float* ws    = (float*)d_ws;
    float* stats = ws + STATS_OFF;  // 384 floats
    float* inter = ws + INTER_OFF;  // [4096, 256]

    float* pred   = (float*)d_out;                 // [4096]
    float* out_pu = pred + BATCH;                  // [4096,128]
    float* out_hu = out_pu + BATCH * DIM;          // [4096,128]
    float* out_pd = out_hu + BATCH * DIM;          // [4096,128]

    // Scratch aliases (all rewritten before final consumers):
    float* z1 = out_pu;   // [4096,128] — live k_gemm1 -> k_gemm2; rewritten by k_final_gather
    float* z2 = inter;    // [4096,64]  — reuses inter (dead after k_gemm1)

    k_front<<<EBLK + BATCH / 2, 256, 0, stream>>>(
        nodes_v, nodes_d, inter_items, top_n_index, prototypes,
        pre_text, pre_visual, Wt, bt, Wv, bv, item_prompt, domain_prompt,
        out_hu, inter, stats);
    k_gemm1<<<dim3(BATCH / 32, 128 / 64), 256, 0, stream>>>(inter, W1, b1, z1, stats);
    k_gemm2<<<BATCH / 16, 256, 0, stream>>>(z1, stats, g1, be1, W2, b2, z2);
    k_final_gather<<<BATCH / 4, 256, 0, stream>>>(z2, stats, g2, be2, Wp, bp,
                                                  nodes_u, nodes_d, user_prompt,
                                                  domain_prompt, pred, out_pu, out_pd);
}